// Round 1
// baseline (457.588 us; speedup 1.0000x reference)
//
#include <hip/hip_runtime.h>
#include <math.h>

// TimeWindowBlock: per (b,w): MLP-score 200 keys vs query, mask, softmax over S,
// weighted-sum keys. Restructured: h_o = A_o + c_o . k  (q folded into c, A).
//
// One block per (b,w) pair (4096 blocks, 256 threads).
// key tile (50KB) staged in LDS with row stride 68 (pad) for conflict-free reads.

#define BB   512
#define WW   8
#define SS   200
#define HH   64
#define FFN  36
#define PAD  68          // key LDS row stride in floats (68*4B rows are 16B aligned)

__global__ __launch_bounds__(256, 2)
void twb_kernel(const float* __restrict__ query,
                const float* __restrict__ key,
                const float* __restrict__ W1,
                const float* __restrict__ b1,
                const float* __restrict__ prelu_a,
                const float* __restrict__ W2,
                const float* __restrict__ b2,
                const int*   __restrict__ mask,
                float*       __restrict__ out)
{
    __shared__ float q_s[HH];
    __shared__ float c_s[FFN * HH];      // c[o][h], 9216 B
    __shared__ float A_s[FFN];
    __shared__ float W2_s[FFN];
    __shared__ float k_s[SS * PAD];      // 54400 B
    __shared__ float wl[256];            // softmax weights
    __shared__ float red[8];
    __shared__ float part[4 * 64];

    const int tid = threadIdx.x;
    const int bw  = blockIdx.x;          // b*8 + w
    const int b   = bw >> 3;

    // ---- stage q, W2 ----
    if (tid < HH)  q_s[tid]  = query[b * HH + tid];
    if (tid < FFN) W2_s[tid] = W2[tid];
    __syncthreads();

    // ---- stage key tile: 3200 float4, coalesced global reads ----
    const float4* gk4 = (const float4*)(key + (size_t)bw * (SS * HH));
    float4* kl4 = (float4*)k_s;
    for (int i = tid; i < (SS * HH) / 4; i += 256) {
        float4 v = gk4[i];
        int s  = i >> 4;                 // 16 float4 per row
        int h4 = i & 15;
        kl4[s * 17 + h4] = v;            // PAD/4 = 17
    }

    // ---- compute c[o][h] = W1[o,H+h] - W1[o,2H+h] + W1[o,3H+h]*q[h] ----
    for (int idx = tid; idx < FFN * HH; idx += 256) {
        int o = idx >> 6, h = idx & 63;
        const float* w = W1 + o * (4 * HH);
        c_s[idx] = w[HH + h] - w[2 * HH + h] + w[3 * HH + h] * q_s[h];
    }
    // ---- A[o] = b1[o] + sum_h (W1[o,h] + W1[o,2H+h]) * q[h] ----
    if (tid < FFN) {
        const float* w = W1 + tid * (4 * HH);
        float a = b1[tid];
        #pragma unroll 8
        for (int h = 0; h < HH; ++h) a += (w[h] + w[2 * HH + h]) * q_s[h];
        A_s[tid] = a;
    }
    __syncthreads();

    // ---- phase 1: score per s (lane = s), key row in registers, c broadcast ----
    const float pa  = prelu_a[0];
    const float bb2 = b2[0];
    float msc = -3.0e38f;
    if (tid < SS) {
        float acc[FFN];
        #pragma unroll
        for (int o = 0; o < FFN; ++o) acc[o] = A_s[o];

        const float4* c4 = (const float4*)c_s;
        const float4* k4 = (const float4*)k_s;
        const int rowbase = tid * 17;

        for (int ch = 0; ch < 4; ++ch) {          // 4 chunks of 16 h
            float4 kv0 = k4[rowbase + ch * 4 + 0];
            float4 kv1 = k4[rowbase + ch * 4 + 1];
            float4 kv2 = k4[rowbase + ch * 4 + 2];
            float4 kv3 = k4[rowbase + ch * 4 + 3];
            #pragma unroll
            for (int o = 0; o < FFN; ++o) {       // full unroll: acc stays in VGPRs
                float4 c0 = c4[o * 16 + ch * 4 + 0];
                float4 c1 = c4[o * 16 + ch * 4 + 1];
                float4 c2 = c4[o * 16 + ch * 4 + 2];
                float4 c3 = c4[o * 16 + ch * 4 + 3];
                float a = acc[o];
                a += c0.x * kv0.x + c0.y * kv0.y + c0.z * kv0.z + c0.w * kv0.w;
                a += c1.x * kv1.x + c1.y * kv1.y + c1.z * kv1.z + c1.w * kv1.w;
                a += c2.x * kv2.x + c2.y * kv2.y + c2.z * kv2.z + c2.w * kv2.w;
                a += c3.x * kv3.x + c3.y * kv3.y + c3.z * kv3.z + c3.w * kv3.w;
                acc[o] = a;
            }
        }
        float sc = bb2;
        #pragma unroll
        for (int o = 0; o < FFN; ++o) {
            float a = acc[o];
            a = (a >= 0.0f) ? a : pa * a;         // PReLU
            sc += W2_s[o] * a;
        }
        int m = mask[bw * SS + tid];
        msc = m ? -10000.0f : sc;
    }

    // ---- softmax over S (block-wide: shuffle within wave, LDS across waves) ----
    float mx = msc;
    #pragma unroll
    for (int off = 32; off > 0; off >>= 1)
        mx = fmaxf(mx, __shfl_xor(mx, off, 64));
    const int wid = tid >> 6;
    if ((tid & 63) == 0) red[wid] = mx;
    __syncthreads();
    const float M = fmaxf(fmaxf(red[0], red[1]), fmaxf(red[2], red[3]));
    float e = (tid < SS) ? __expf(msc - M) : 0.0f;
    float ssum = e;
    #pragma unroll
    for (int off = 32; off > 0; off >>= 1)
        ssum += __shfl_xor(ssum, off, 64);
    if ((tid & 63) == 0) red[4 + wid] = ssum;
    __syncthreads();
    const float total = red[4] + red[5] + red[6] + red[7];
    if (tid < SS) wl[tid] = e / total;
    __syncthreads();

    // ---- phase 2: out[h] = sum_s k[s][h] * w[s]; split s over 4 waves ----
    const int wv = tid >> 6, h = tid & 63;
    float p = 0.0f;
    #pragma unroll 5
    for (int s = wv * 50; s < wv * 50 + 50; ++s)
        p += k_s[s * PAD + h] * wl[s];
    part[wv * 64 + h] = p;
    __syncthreads();
    if (tid < 64) {
        float r = part[tid] + part[64 + tid] + part[128 + tid] + part[192 + tid];
        out[(size_t)bw * HH + tid] = r;
    }
}

extern "C" void kernel_launch(void* const* d_in, const int* in_sizes, int n_in,
                              void* d_out, int out_size, void* d_ws, size_t ws_size,
                              hipStream_t stream) {
    const float* query   = (const float*)d_in[0];
    const float* key     = (const float*)d_in[1];
    const float* W1      = (const float*)d_in[2];
    const float* b1      = (const float*)d_in[3];
    const float* prelu_a = (const float*)d_in[4];
    const float* W2      = (const float*)d_in[5];
    const float* b2      = (const float*)d_in[6];
    const int*   mask    = (const int*)d_in[7];
    float* out = (float*)d_out;

    twb_kernel<<<BB * WW, 256, 0, stream>>>(query, key, W1, b1, prelu_a,
                                            W2, b2, mask, out);
}